// Round 1
// baseline (124.874 us; speedup 1.0000x reference)
//
#include <hip/hip_runtime.h>
#include <hip/hip_bf16.h>

#define BS 16384
#define D  512
#define MARGIN 1.0f

// One wave (64 lanes) per triplet row. D=512 fp32 -> 128 float4 per row ->
// 2 float4 per lane per vector. Coalesced: 64 lanes x 16B = 1KB per load instr.
__global__ __launch_bounds__(256) void TripletLoss_58231166599209_kernel(
    const float* __restrict__ batch,
    const int*   __restrict__ triplets,
    float* __restrict__ out)
{
    const int tid   = blockIdx.x * blockDim.x + threadIdx.x;
    const int row   = tid >> 6;          // global wave id = triplet row
    const int lane  = threadIdx.x & 63;
    const int waveInBlk = threadIdx.x >> 6;

    __shared__ float s_part[4];          // 4 waves per 256-thread block

    float dap = 0.0f, dan = 0.0f;

    if (row < BS) {
        const int t0 = triplets[row * 3 + 0];
        const int t1 = triplets[row * 3 + 1];
        const int t2 = triplets[row * 3 + 2];

        const float4* __restrict__ a = (const float4*)(batch + (size_t)t0 * D);
        const float4* __restrict__ p = (const float4*)(batch + (size_t)t1 * D);
        const float4* __restrict__ n = (const float4*)(batch + (size_t)t2 * D);

        // Two strided chunks: j = lane, lane+64  (D/4 = 128)
        #pragma unroll
        for (int k = 0; k < 2; ++k) {
            const int j = lane + 64 * k;
            const float4 av = a[j];
            const float4 pv = p[j];
            const float4 nv = n[j];

            float d;
            d = av.x - pv.x; dap += d * d;
            d = av.y - pv.y; dap += d * d;
            d = av.z - pv.z; dap += d * d;
            d = av.w - pv.w; dap += d * d;

            d = av.x - nv.x; dan += d * d;
            d = av.y - nv.y; dan += d * d;
            d = av.z - nv.z; dan += d * d;
            d = av.w - nv.w; dan += d * d;
        }
    }

    // Wave-level butterfly reduction over 64 lanes
    #pragma unroll
    for (int off = 32; off > 0; off >>= 1) {
        dap += __shfl_down(dap, off, 64);
        dan += __shfl_down(dan, off, 64);
    }

    if (lane == 0) {
        float loss = dap - dan + MARGIN;
        s_part[waveInBlk] = (loss > 0.0f) ? loss : 0.0f;
    }
    __syncthreads();

    if (threadIdx.x == 0) {
        float blk = s_part[0] + s_part[1] + s_part[2] + s_part[3];
        atomicAdd(out, blk);   // device-scope by default on CDNA
    }
}

extern "C" void kernel_launch(void* const* d_in, const int* in_sizes, int n_in,
                              void* d_out, int out_size, void* d_ws, size_t ws_size,
                              hipStream_t stream) {
    const float* batch    = (const float*)d_in[0];
    const int*   triplets = (const int*)d_in[1];
    float*       out      = (float*)d_out;

    // d_out is poisoned with 0xAA before every timed call — zero it.
    hipMemsetAsync(out, 0, sizeof(float), stream);

    // 1 wave per row, 4 waves per block -> BS/4 blocks
    dim3 grid(BS / 4);
    dim3 block(256);
    TripletLoss_58231166599209_kernel<<<grid, block, 0, stream>>>(batch, triplets, out);
}

// Round 2
// 83.270 us; speedup vs baseline: 1.4996x; 1.4996x over previous
//
#include <hip/hip_runtime.h>

#define BS 16384
#define D  512
#define MARGIN 1.0f

#define RPW 4                  // rows per wave
#define WPB 4                  // waves per block (256 threads)
#define RPB (RPW * WPB)        // 16 rows per block
#define NBLK (BS / RPB)        // 1024 blocks

// Stage 1: per-block partial sums of relu(d_ap - d_an + margin).
// One wave handles 4 consecutive rows (unrolled -> 24 independent float4
// load-triples in flight per wave for latency hiding).
__global__ __launch_bounds__(256) void triplet_partial(
    const float* __restrict__ batch,
    const int*   __restrict__ triplets,
    float* __restrict__ partial)
{
    const int lane = threadIdx.x & 63;
    const int wib  = threadIdx.x >> 6;
    const int rowBase = (blockIdx.x * WPB + wib) * RPW;

    __shared__ float s_part[WPB];

    float waveLoss = 0.0f;   // meaningful on lane 0 only

    #pragma unroll
    for (int r = 0; r < RPW; ++r) {
        const int row = rowBase + r;
        const int t0 = triplets[row * 3 + 0];
        const int t1 = triplets[row * 3 + 1];
        const int t2 = triplets[row * 3 + 2];

        const float4* __restrict__ a = (const float4*)(batch + (size_t)t0 * D);
        const float4* __restrict__ p = (const float4*)(batch + (size_t)t1 * D);
        const float4* __restrict__ n = (const float4*)(batch + (size_t)t2 * D);

        // Single fused accumulator: sum((a-p)^2 - (a-n)^2)
        float acc = 0.0f;
        #pragma unroll
        for (int k = 0; k < 2; ++k) {
            const int j = lane + 64 * k;          // D/4 = 128 float4 per row
            const float4 av = a[j];
            const float4 pv = p[j];
            const float4 nv = n[j];
            float dp, dn;
            dp = av.x - pv.x; dn = av.x - nv.x; acc += dp * dp - dn * dn;
            dp = av.y - pv.y; dn = av.y - nv.y; acc += dp * dp - dn * dn;
            dp = av.z - pv.z; dn = av.z - nv.z; acc += dp * dp - dn * dn;
            dp = av.w - pv.w; dn = av.w - nv.w; acc += dp * dp - dn * dn;
        }

        // Wave reduction of one value (6 shuffle levels)
        #pragma unroll
        for (int off = 32; off > 0; off >>= 1)
            acc += __shfl_down(acc, off, 64);

        if (lane == 0) {
            const float loss = acc + MARGIN;
            waveLoss += (loss > 0.0f) ? loss : 0.0f;
        }
    }

    if (lane == 0) s_part[wib] = waveLoss;
    __syncthreads();
    if (threadIdx.x == 0)
        partial[blockIdx.x] = s_part[0] + s_part[1] + s_part[2] + s_part[3];
}

// Stage 2: reduce NBLK partials -> out[0]. Single block, no atomics, no memset.
__global__ __launch_bounds__(256) void triplet_reduce(
    const float* __restrict__ partial,
    float* __restrict__ out)
{
    const int lane = threadIdx.x & 63;
    const int wib  = threadIdx.x >> 6;

    float acc = 0.0f;
    #pragma unroll
    for (int i = threadIdx.x; i < NBLK; i += 256)
        acc += partial[i];

    #pragma unroll
    for (int off = 32; off > 0; off >>= 1)
        acc += __shfl_down(acc, off, 64);

    __shared__ float s[4];
    if (lane == 0) s[wib] = acc;
    __syncthreads();
    if (threadIdx.x == 0)
        out[0] = s[0] + s[1] + s[2] + s[3];
}

extern "C" void kernel_launch(void* const* d_in, const int* in_sizes, int n_in,
                              void* d_out, int out_size, void* d_ws, size_t ws_size,
                              hipStream_t stream) {
    const float* batch    = (const float*)d_in[0];
    const int*   triplets = (const int*)d_in[1];
    float*       out      = (float*)d_out;
    float*       partial  = (float*)d_ws;    // NBLK floats = 4 KB scratch

    triplet_partial<<<NBLK, 256, 0, stream>>>(batch, triplets, partial);
    triplet_reduce<<<1, 256, 0, stream>>>(partial, out);
}

// Round 3
// 81.846 us; speedup vs baseline: 1.5257x; 1.0174x over previous
//
#include <hip/hip_runtime.h>

#define BS 16384
#define D  512
#define MARGIN 1.0f

#define RPW 4                  // rows per wave
#define WPB 4                  // waves per block (256 threads)
#define RPB (RPW * WPB)        // 16 rows per block
#define NBLK (BS / RPB)        // 1024 blocks

// Stage 1: per-block partial sums of relu(d_ap - d_an + margin).
// Structure: (1) preload all 12 wave-uniform indices -> row bases live in
// SGPRs; (2) issue all 24 float4 loads back-to-back (max outstanding vmem);
// (3) FMA into 4 independent accumulators; (4) interleave the 4 shuffle
// chains so ds latency overlaps 4-wide instead of serializing per row.
__global__ __launch_bounds__(256) void triplet_partial(
    const float* __restrict__ batch,
    const int*   __restrict__ triplets,
    float* __restrict__ partial)
{
    const int lane = threadIdx.x & 63;
    const int wib  = threadIdx.x >> 6;
    const int rowBase = (blockIdx.x * WPB + wib) * RPW;

    __shared__ float s_part[WPB];

    // (1) preload indices (wave-uniform -> scalar loads)
    int t0[RPW], t1[RPW], t2[RPW];
    #pragma unroll
    for (int r = 0; r < RPW; ++r) {
        t0[r] = triplets[(rowBase + r) * 3 + 0];
        t1[r] = triplets[(rowBase + r) * 3 + 1];
        t2[r] = triplets[(rowBase + r) * 3 + 2];
    }

    // (2) issue all loads: 4 rows x 3 ptrs x 2 chunks = 24 float4
    float4 av[RPW][2], pv[RPW][2], nv[RPW][2];
    #pragma unroll
    for (int r = 0; r < RPW; ++r) {
        const float4* __restrict__ a = (const float4*)(batch + (size_t)t0[r] * D);
        const float4* __restrict__ p = (const float4*)(batch + (size_t)t1[r] * D);
        const float4* __restrict__ n = (const float4*)(batch + (size_t)t2[r] * D);
        #pragma unroll
        for (int k = 0; k < 2; ++k) {
            const int j = lane + 64 * k;     // D/4 = 128 float4 per row
            av[r][k] = a[j];
            pv[r][k] = p[j];
            nv[r][k] = n[j];
        }
    }

    // (3) per-lane partials: sum((a-p)^2 - (a-n)^2), one acc per row
    float acc[RPW];
    #pragma unroll
    for (int r = 0; r < RPW; ++r) {
        float s = 0.0f;
        #pragma unroll
        for (int k = 0; k < 2; ++k) {
            float dp, dn;
            dp = av[r][k].x - pv[r][k].x; dn = av[r][k].x - nv[r][k].x; s += dp * dp - dn * dn;
            dp = av[r][k].y - pv[r][k].y; dn = av[r][k].y - nv[r][k].y; s += dp * dp - dn * dn;
            dp = av[r][k].z - pv[r][k].z; dn = av[r][k].z - nv[r][k].z; s += dp * dp - dn * dn;
            dp = av[r][k].w - pv[r][k].w; dn = av[r][k].w - nv[r][k].w; s += dp * dp - dn * dn;
        }
        acc[r] = s;
    }

    // (4) interleaved wave reductions: 4 independent ds chains per level
    #pragma unroll
    for (int off = 32; off > 0; off >>= 1) {
        #pragma unroll
        for (int r = 0; r < RPW; ++r)
            acc[r] += __shfl_down(acc[r], off, 64);
    }

    if (lane == 0) {
        float waveLoss = 0.0f;
        #pragma unroll
        for (int r = 0; r < RPW; ++r) {
            const float loss = acc[r] + MARGIN;
            waveLoss += (loss > 0.0f) ? loss : 0.0f;
        }
        s_part[wib] = waveLoss;
    }
    __syncthreads();
    if (threadIdx.x == 0)
        partial[blockIdx.x] = s_part[0] + s_part[1] + s_part[2] + s_part[3];
}

// Stage 2: reduce NBLK partials -> out[0]. Single block, float4 loads.
__global__ __launch_bounds__(256) void triplet_reduce(
    const float* __restrict__ partial,
    float* __restrict__ out)
{
    const int lane = threadIdx.x & 63;
    const int wib  = threadIdx.x >> 6;

    // 1024 floats = 256 float4, one per thread
    const float4 v = ((const float4*)partial)[threadIdx.x];
    float acc = v.x + v.y + v.z + v.w;

    #pragma unroll
    for (int off = 32; off > 0; off >>= 1)
        acc += __shfl_down(acc, off, 64);

    __shared__ float s[4];
    if (lane == 0) s[wib] = acc;
    __syncthreads();
    if (threadIdx.x == 0)
        out[0] = s[0] + s[1] + s[2] + s[3];
}

extern "C" void kernel_launch(void* const* d_in, const int* in_sizes, int n_in,
                              void* d_out, int out_size, void* d_ws, size_t ws_size,
                              hipStream_t stream) {
    const float* batch    = (const float*)d_in[0];
    const int*   triplets = (const int*)d_in[1];
    float*       out      = (float*)d_out;
    float*       partial  = (float*)d_ws;    // NBLK floats = 4 KB scratch

    triplet_partial<<<NBLK, 256, 0, stream>>>(batch, triplets, partial);
    triplet_reduce<<<1, 256, 0, stream>>>(partial, out);
}